// Round 5
// baseline (475.444 us; speedup 1.0000x reference)
//
#include <hip/hip_runtime.h>
#include <hip/hip_bf16.h>
#include <stdint.h>

// XL multihead attention, L=S=2048, N=4, E=512, H=8, D=64.  I/O = fp32.
// _rel_shift collapses to a per-row constant (softmax-invariant) => term_bd,
// rel_v, sin_pos_enc, rel_proj_w drop out. Remaining: MHA with rel_u q-bias
// + head-mean att weights.
// R10: flash_pv + attw_k go LDS-FREE. All MFMA fragments are contiguous 16B
// runs in Kw[s][d] / Vt[d][s] / Qw[l][d], and K/V are L2-resident (FETCH=12MB
// proved it) with 4 waves/block reading the same tile (L1 broadcast). Direct
// global fragment loads remove every barrier, every LDS op, all conflicts,
// and the LDS occupancy cap. Numerics bit-identical.

#define L_Q 2048
#define S_K 2048
#define N_B 4
#define E_D 512
#define H_N 8
#define D_H 64

typedef unsigned short u16;
typedef unsigned int u32;
typedef short v8s __attribute__((ext_vector_type(8)));
typedef float v4f __attribute__((ext_vector_type(4)));
typedef float v16f __attribute__((ext_vector_type(16)));
typedef u32 v4u __attribute__((ext_vector_type(4)));

#define MFMA16(a, b, c) __builtin_amdgcn_mfma_f32_16x16x32_bf16(a, b, c, 0, 0, 0)
#define MFMA32(a, b, c) __builtin_amdgcn_mfma_f32_32x32x16_bf16(a, b, c, 0, 0, 0)

__device__ __forceinline__ float bf2f(u16 u) {
  unsigned int x = ((unsigned int)u) << 16;
  return __builtin_bit_cast(float, x);
}
__device__ __forceinline__ u16 f2bf(float f) {  // RNE
  unsigned int x = __builtin_bit_cast(unsigned int, f);
  x += 0x7FFFu + ((x >> 16) & 1u);
  return (u16)(x >> 16);
}

// p = exp(sv/8) = exp2(sv * 0.125*log2(e)), arg clamped to +-43.28 (= exp +-30)
__device__ __forceinline__ float expfast(float sv) {
  const float x =
      __builtin_amdgcn_fmed3f(sv * 0.18033688011112042f, -43.2809f, 43.2809f);
#if __has_builtin(__builtin_amdgcn_exp2f)
  return __builtin_amdgcn_exp2f(x);
#else
  return __expf(x * 0.6931471805599453f);
#endif
}

// pack two f32 -> u32 of 2 bf16 (lo = first arg), RNE
__device__ __forceinline__ u32 cvtpk(float lo, float hi) {
  u32 r;
  asm("v_cvt_pk_bf16_f32 %0, %1, %2" : "=v"(r) : "v"(lo), "v"(hi));
  return r;
}

// a.upper <-> b.lower (lanes 32-63 of a get b's lanes 0-31, and vice versa)
__device__ __forceinline__ void plswap(u32& a, u32& b) {
  asm volatile("v_permlane32_swap_b32 %0, %1" : "+v"(a), "+v"(b));
}

#if __has_builtin(__builtin_amdgcn_global_load_lds)
#define HAVE_GLDS 1
// dest is wave-uniform base; HW writes lane i at base + i*16B
__device__ __forceinline__ void glds16(const u16* g, u16* l) {
  __builtin_amdgcn_global_load_lds(
      (const __attribute__((address_space(1))) void*)g,
      (__attribute__((address_space(3))) void*)l, 16, 0, 0);
}
#else
#define HAVE_GLDS 0
#endif

// ---- bulk fp32 -> bf16 converter over 8 segments ----
struct Cvt8 {
  const float* s[8];
  u16* d[8];
};
__global__ __launch_bounds__(256) void cvt_k(Cvt8 a) {
  const size_t t = ((size_t)blockIdx.x * 256 + threadIdx.x) * 4;
  const size_t cum[9] = {0,        4194304,  8388608,  12582912, 13369344,
                         13631488, 13633024, 13633536, 13634048};
  if (t >= cum[8]) return;
  int sg = 0;
#pragma unroll
  for (int i = 1; i < 8; i++) sg += (t >= cum[i]);
  const size_t off = t - cum[sg];
  const v4f x = *(const v4f*)(a.s[sg] + off);
  ushort4 o;
  o.x = f2bf(x[0]);
  o.y = f2bf(x[1]);
  o.z = f2bf(x[2]);
  o.w = f2bf(x[3]);
  *(ushort4*)(a.d[sg] + off) = o;
}

// ---------------- NT GEMM core: C(128x128) = A(Mx512) * W(512 rows)^T ------
__device__ __forceinline__ void gemm_core(const u16* A, const u16* W, int m0,
                                          int n0, u16* As, u16* Bs,
                                          v4f acc[4][4]) {
  const int lane = threadIdx.x & 63;
  const int w = threadIdx.x >> 6;
  const int wr = w >> 1, wc = w & 1;
  const int q = lane >> 4, c = lane & 15;
#pragma unroll
  for (int i = 0; i < 4; i++)
#pragma unroll
    for (int j = 0; j < 4; j++) acc[i][j] = (v4f){0.f, 0.f, 0.f, 0.f};
  for (int kk = 0; kk < 16; ++kk) {
    const u16* ga = A + (size_t)(m0 + lane) * E_D + kk * 32 + w * 8;
    const u16* gb = W + (size_t)(n0 + lane) * E_D + kk * 32 + w * 8;
#if HAVE_GLDS
    __syncthreads();  // prior iteration's reads done before overwrite
    glds16(ga, As + w * 1032);
    glds16(ga + 64 * E_D, As + w * 1032 + 512);
    glds16(gb, Bs + w * 1032);
    glds16(gb + 64 * E_D, Bs + w * 1032 + 512);
    __syncthreads();  // drains vmcnt -> LDS ready
#else
    const v8s va0 = *(const v8s*)ga;
    const v8s va1 = *(const v8s*)(ga + 64 * E_D);
    const v8s vb0 = *(const v8s*)gb;
    const v8s vb1 = *(const v8s*)(gb + 64 * E_D);
    __syncthreads();
    *(v8s*)(As + w * 1032 + lane * 8) = va0;
    *(v8s*)(As + w * 1032 + 512 + lane * 8) = va1;
    *(v8s*)(Bs + w * 1032 + lane * 8) = vb0;
    *(v8s*)(Bs + w * 1032 + 512 + lane * 8) = vb1;
    __syncthreads();
#endif
    v8s a[4], b[4];
#pragma unroll
    for (int i = 0; i < 4; i++)
      a[i] = *(const v8s*)(As + q * 1032 + (wr * 64 + i * 16 + c) * 8);
#pragma unroll
    for (int j = 0; j < 4; j++)
      b[j] = *(const v8s*)(Bs + q * 1032 + (wc * 64 + j * 16 + c) * 8);
#pragma unroll
    for (int i = 0; i < 4; i++)
#pragma unroll
      for (int j = 0; j < 4; j++) acc[i][j] = MFMA16(a[i], b[j], acc[i][j]);
  }
}

// qkv projections (all-bf16). z=0: Qw[n][h][l][d] = q + bias + rel_u
//   z=1: Kw[n][h][s][d]   z=2: Vt[n][h][d][s] (transposed for PV)
__global__ __launch_bounds__(256) void gemm_qkv(
    const u16* __restrict__ qb, const u16* __restrict__ kb,
    const u16* __restrict__ vb, const u16* __restrict__ Wallb,
    const u16* __restrict__ biasb, const u16* __restrict__ rel_ub,
    u16* __restrict__ Qw, u16* __restrict__ Kw, u16* __restrict__ Vt) {
  __shared__ __align__(16) u16 As[4 * 1032];
  __shared__ __align__(16) u16 Bs[4 * 1032];
  const int z = blockIdx.z;
  const u16* A = (z == 0) ? qb : ((z == 1) ? kb : vb);
  const int m0 = blockIdx.x * 128, n0 = blockIdx.y * 128;
  v4f acc[4][4];
  gemm_core(A, Wallb + (size_t)z * E_D * E_D, m0, n0, As, Bs, acc);
  const int lane = threadIdx.x & 63, w = threadIdx.x >> 6;
  const int wr = w >> 1, wc = w & 1;
  const int q = lane >> 4, c = lane & 15;
#pragma unroll
  for (int j = 0; j < 4; j++) {
    const int jg = n0 + wc * 64 + j * 16 + c;  // output feature = h*64+d
    const int h = jg >> 6, d = jg & 63;
    float add =
        bf2f(biasb[z * E_D + jg]) + ((z == 0) ? bf2f(rel_ub[jg]) : 0.f);
#pragma unroll
    for (int i = 0; i < 4; i++) {
#pragma unroll
      for (int r = 0; r < 4; r++) {
        const int mg = m0 + wr * 64 + i * 16 + q * 4 + r;  // row = l*4+n
        const int row = mg >> 2, nn = mg & 3;
        const u16 o = f2bf(acc[i][j][r] + add);
        if (z == 0)
          Qw[((size_t)(nn * H_N + h) * L_Q + row) * D_H + d] = o;
        else if (z == 1)
          Kw[((size_t)(nn * H_N + h) * S_K + row) * D_H + d] = o;
        else
          Vt[((size_t)(nn * H_N + h) * D_H + d) * S_K + row] = o;
      }
    }
  }
}

// out = Actx(8192x512)bf16 @ Woutb^T + bout -> fp32 d_out[0 : L*N*E)
__global__ __launch_bounds__(256) void gemm_out(const u16* __restrict__ Actx,
                                                const u16* __restrict__ Woutb,
                                                const u16* __restrict__ boutb,
                                                float* __restrict__ out) {
  __shared__ __align__(16) u16 As[4 * 1032];
  __shared__ __align__(16) u16 Bs[4 * 1032];
  const int m0 = blockIdx.x * 128, n0 = blockIdx.y * 128;
  v4f acc[4][4];
  gemm_core(Actx, Woutb, m0, n0, As, Bs, acc);
  const int lane = threadIdx.x & 63, w = threadIdx.x >> 6;
  const int wr = w >> 1, wc = w & 1;
  const int q = lane >> 4, c = lane & 15;
#pragma unroll
  for (int j = 0; j < 4; j++) {
    const int jg = n0 + wc * 64 + j * 16 + c;
    const float bb = bf2f(boutb[jg]);
#pragma unroll
    for (int i = 0; i < 4; i++) {
#pragma unroll
      for (int r = 0; r < 4; r++) {
        const int mg = m0 + wr * 64 + i * 16 + q * 4 + r;
        out[(size_t)mg * E_D + jg] = acc[i][j][r] + bb;
      }
    }
  }
}

// Flash pass, 32x32x16, LDS-FREE. Block = 128 l (32 per wave), chunk = 64 s.
// QK^T as mfma(K,Q) => D = S^T[s][l], lane holds 32 s-values for its own l.
// K fragment rows are 16B-contiguous in Kw[s][d]; V fragment rows are
// 16B-contiguous in Vt[d][s] -> direct global loads (L2-resident, all 4
// waves read the same tile -> L1 broadcast). No barriers, no LDS at all.
// P in-register: expfast -> cvt_pk bf16 pairs -> permlane32_swap.
__global__ __launch_bounds__(256) void flash_pv(
    const u16* __restrict__ Qw, const u16* __restrict__ Kw,
    const u16* __restrict__ Vt, u16* __restrict__ Actx,
    float* __restrict__ Rbuf) {
  const int lane = threadIdx.x & 63, w = threadIdx.x >> 6;
  const int ln = lane & 31, hi = lane >> 5;
  // bijective XCD swizzle: 512 blocks = 8 xcd * 64; xcd gets 4 contig nh's
  const int orig = (blockIdx.x & 7) * 64 + (blockIdx.x >> 3);
  const int l0 = (orig & 15) * 128;
  const int h = (orig >> 4) & 7;
  const int n = orig >> 7;
  const int nh = n * H_N + h;
  // Q B-fragments direct from global (row l, k = d = kt*16 + hi*8 + j)
  v8s aq[4];
  {
    const u16* gq = Qw + ((size_t)nh * L_Q + l0 + w * 32 + ln) * D_H + hi * 8;
#pragma unroll
    for (int kt = 0; kt < 4; kt++) aq[kt] = *(const v8s*)(gq + kt * 16);
  }
  const u16* kbase = Kw + ((size_t)nh * S_K + ln) * D_H + hi * 8;
  const u16* vbase = Vt + ((size_t)nh * D_H + ln) * S_K + hi * 8;
  v16f ctx[2];
  ctx[0] = (v16f)0.f;
  ctx[1] = (v16f)0.f;
  float s_run = 0.f;
  for (int s0 = 0; s0 < S_K; s0 += 64) {
    // QK: two 32-s tiles; A = K[s = s0+st*32+ln][d = kt*16+hi*8+j] direct
    v8s pb[4];  // PV B-frags: P^T slot ks covers s = ks*16 + hi*8 + j
#pragma unroll
    for (int st = 0; st < 2; st++) {
      v16f zz = (v16f)0.f;
#pragma unroll
      for (int kt = 0; kt < 4; kt++) {
        const v8s bk =
            *(const v8s*)(kbase + (size_t)(s0 + st * 32) * D_H + kt * 16);
        zz = MFMA32(bk, aq[kt], zz);
      }
      // lane's s-coverage: st*32 + (r&3) + 8*(r>>2) + 4*hi, r = 0..15
      float pv[16];
#pragma unroll
      for (int r = 0; r < 16; r++) {
        pv[r] = expfast(zz[r]);
        s_run += pv[r];
      }
#pragma unroll
      for (int half = 0; half < 2; half++) {
        const int rb = half * 8;
        u32 a0 = cvtpk(pv[rb + 0], pv[rb + 1]);
        u32 b0 = cvtpk(pv[rb + 4], pv[rb + 5]);
        u32 a1 = cvtpk(pv[rb + 2], pv[rb + 3]);
        u32 b1 = cvtpk(pv[rb + 6], pv[rb + 7]);
        plswap(a0, b0);  // a0 -> word0 (s+0,1|8,9), b0 -> word2 (s+4,5|12,13)
        plswap(a1, b1);  // a1 -> word1,  b1 -> word3
        v4u t;
        t.x = a0;
        t.y = a1;
        t.z = b0;
        t.w = b1;
        pb[st * 2 + half] = __builtin_bit_cast(v8s, t);
      }
    }
    // PV: O^T[d][l]; A = V^T[d = dt*32+ln][s = s0+ks*16+hi*8+j] direct
#pragma unroll
    for (int dt = 0; dt < 2; dt++) {
#pragma unroll
      for (int ks = 0; ks < 4; ks++) {
        const v8s av =
            *(const v8s*)(vbase + (size_t)(dt * 32) * S_K + s0 + ks * 16);
        ctx[dt] = MFMA32(av, pb[ks], ctx[dt]);
      }
    }
  }
  // full row sum: lane covers half the s-values, partner lane^32 the rest
  const float s = s_run + __shfl_xor(s_run, 32);
  const float rr = 1.0f / s;
  const int l = l0 + w * 32 + ln;
  u16* pout = Actx + ((size_t)l * N_B + n) * E_D + h * D_H;
#pragma unroll
  for (int dt = 0; dt < 2; dt++) {
#pragma unroll
    for (int g = 0; g < 4; g++) {
      const int d = dt * 32 + g * 8 + hi * 4;  // 4 consecutive d per group
      uint2 o;
      o.x = cvtpk(ctx[dt][g * 4 + 0] * rr, ctx[dt][g * 4 + 1] * rr);
      o.y = cvtpk(ctx[dt][g * 4 + 2] * rr, ctx[dt][g * 4 + 3] * rr);
      *(uint2*)(pout + d) = o;
    }
  }
  if (hi == 0) Rbuf[(size_t)nh * L_Q + l] = rr;  // 32 consecutive floats
}

// attw pass (runs LAST; overwrites the d_out scratch region with the real
// attention-weight output), LDS-FREE: per (n, l-tile 64, s-chunk 256): loop
// 8 heads, recompute scores with fragments loaded directly from Qw/Kw
// (16B-contiguous in d at fixed row; K tile shared by all 4 waves -> L1),
// accumulate expfast(s)*r, write mean/8 fp32. No barriers, no LDS.
// aw indices all compile-time (rule #20).
__global__ __launch_bounds__(256) void attw_k(const u16* __restrict__ Qw,
                                              const u16* __restrict__ Kw,
                                              const float* __restrict__ Rbuf,
                                              float* __restrict__ AW) {
  const int lane = threadIdx.x & 63, w = threadIdx.x >> 6;
  const int q = lane >> 4, c = lane & 15;
  const int s_base = blockIdx.x * 256;
  const int l0 = blockIdx.y * 64;
  const int n = blockIdx.z;
  v4f aw[4][4];
#pragma unroll
  for (int ss = 0; ss < 4; ss++)
#pragma unroll
    for (int jt = 0; jt < 4; jt++) aw[ss][jt] = (v4f){0.f, 0.f, 0.f, 0.f};
  for (int h = 0; h < H_N; ++h) {
    const int nh = n * H_N + h;
    // Q B-fragment direct: row l = l0 + w*16 + c, d = q*8(+32)
    const u16* gq = Qw + ((size_t)nh * L_Q + l0 + w * 16 + c) * D_H + q * 8;
    const v8s aq0 = *(const v8s*)gq;
    const v8s aq1 = *(const v8s*)(gq + 32);
    float rr[4];
#pragma unroll
    for (int r = 0; r < 4; r++)
      rr[r] = Rbuf[(size_t)nh * L_Q + l0 + w * 16 + q * 4 + r];
    const u16* kb0 = Kw + ((size_t)nh * S_K + s_base + c) * D_H + q * 8;
#pragma unroll
    for (int ss = 0; ss < 4; ++ss) {
#pragma unroll
      for (int jt = 0; jt < 4; jt++) {
        // K A-fragment direct: row s = s_base + ss*64 + jt*16 + c
        const u16* gk = kb0 + (size_t)(ss * 64 + jt * 16) * D_H;
        const v8s bk0 = *(const v8s*)gk;
        const v8s bk1 = *(const v8s*)(gk + 32);
        v4f zz = (v4f){0.f, 0.f, 0.f, 0.f};
        zz = MFMA16(aq0, bk0, zz);
        zz = MFMA16(aq1, bk1, zz);
#pragma unroll
        for (int r = 0; r < 4; r++) aw[ss][jt][r] += expfast(zz[r]) * rr[r];
      }
    }
  }
#pragma unroll
  for (int ss = 0; ss < 4; ss++)
#pragma unroll
    for (int jt = 0; jt < 4; jt++)
#pragma unroll
      for (int r = 0; r < 4; r++) {
        const int l = l0 + w * 16 + q * 4 + r;
        const int s = s_base + ss * 64 + jt * 16 + c;
        AW[((size_t)n * L_Q + l) * S_K + s] = aw[ss][jt][r] * 0.125f;
      }
}

extern "C" void kernel_launch(void* const* d_in, const int* in_sizes, int n_in,
                              void* d_out, int out_size, void* d_ws,
                              size_t ws_size, hipStream_t stream) {
  // ws layout (<= 29.7 MB, proven safe at 33.8 in R4)
  char* ws = (char*)d_ws;
  u16* Wallb = (u16*)(ws);                 // 1.57 MB
  u16* Woutb = (u16*)(ws + 1572864);       // 0.52 MB
  u16* biasb = (u16*)(ws + 2097152);       // 3 KB
  u16* boutb = (u16*)(ws + 2100224);       // 1 KB
  u16* rel_ub = (u16*)(ws + 2101248);      // 1 KB
  u16* Qw = (u16*)(ws + 4194304);          // 8 MB (N,H,L,D)
  u16* Kw = (u16*)(ws + 12582912);         // 8 MB (N,H,S,D)
  u16* Vt = (u16*)(ws + 20971520);         // 8 MB (N,H,D,S)
  float* Rbuf = (float*)(ws + 29360128);   // 256 KB (N*H, L)

  // scratch inside d_out's attw region (67 MB; overwritten by attw_k LAST)
  float* out = (float*)d_out;
  char* sc = (char*)d_out + 16777216;
  u16* qb = (u16*)(sc);              // 8 MB converted query
  u16* kb = (u16*)(sc + 8388608);    // 8 MB converted key
  u16* vb = (u16*)(sc + 16777216);   // 8 MB converted value
  u16* Actx = (u16*)(sc + 25165824); // 8 MB context (L*4+n, E)
  float* AW = out + (size_t)L_Q * N_B * E_D;

  Cvt8 a;
  a.s[0] = (const float*)d_in[0];  a.d[0] = qb;      // query
  a.s[1] = (const float*)d_in[1];  a.d[1] = kb;      // key
  a.s[2] = (const float*)d_in[2];  a.d[2] = vb;      // value
  a.s[3] = (const float*)d_in[4];  a.d[3] = Wallb;   // in_proj_weight
  a.s[4] = (const float*)d_in[6];  a.d[4] = Woutb;   // out_w
  a.s[5] = (const float*)d_in[5];  a.d[5] = biasb;   // in_proj_bias
  a.s[6] = (const float*)d_in[7];  a.d[6] = boutb;   // out_b
  a.s[7] = (const float*)d_in[9];  a.d[7] = rel_ub;  // rel_u
  // d_in[3] sin_pos_enc, d_in[8] rel_proj_w, d_in[10] rel_v: algebraically out

  hipLaunchKernelGGL(cvt_k, dim3(13315), dim3(256), 0, stream, a);
  hipLaunchKernelGGL(gemm_qkv, dim3(64, 4, 3), dim3(256), 0, stream, qb, kb,
                     vb, Wallb, biasb, rel_ub, Qw, Kw, Vt);
  hipLaunchKernelGGL(flash_pv, dim3(512), dim3(256), 0, stream, Qw, Kw, Vt,
                     Actx, Rbuf);
  hipLaunchKernelGGL(gemm_out, dim3(64, 4, 1), dim3(256), 0, stream, Actx,
                     Woutb, boutb, out);
  hipLaunchKernelGGL(attw_k, dim3(8, 32, 4), dim3(256), 0, stream, Qw, Kw,
                     Rbuf, AW);
}

// Round 6
// 307.914 us; speedup vs baseline: 1.5441x; 1.5441x over previous
//
#include <hip/hip_runtime.h>
#include <hip/hip_bf16.h>
#include <stdint.h>

// XL multihead attention, L=S=2048, N=4, E=512, H=8, D=64.  I/O = fp32.
// _rel_shift collapses to a per-row constant (softmax-invariant) => term_bd,
// rel_v, sin_pos_enc, rel_proj_w drop out. Remaining: MHA with rel_u q-bias
// + head-mean att weights.
// R11: REVERT flash_pv/attw_k to R9 (R10's LDS-free direct-global fragments
// regressed 3x: L1/TCP path is ~2x slower than LDS per read and pays on
// every fragment re-read; LDS staging amortizes). NEW: gemm_core BK=64 --
// stage 2 k-octet groups per round (8 glds/wave), halving barriers 32->16
// per block; LDS 33KB keeps 4 blocks/CU; fragment reads unchanged.

#define L_Q 2048
#define S_K 2048
#define N_B 4
#define E_D 512
#define H_N 8
#define D_H 64

typedef unsigned short u16;
typedef unsigned int u32;
typedef short v8s __attribute__((ext_vector_type(8)));
typedef float v4f __attribute__((ext_vector_type(4)));
typedef float v16f __attribute__((ext_vector_type(16)));
typedef u32 v4u __attribute__((ext_vector_type(4)));

#define MFMA16(a, b, c) __builtin_amdgcn_mfma_f32_16x16x32_bf16(a, b, c, 0, 0, 0)
#define MFMA32(a, b, c) __builtin_amdgcn_mfma_f32_32x32x16_bf16(a, b, c, 0, 0, 0)

__device__ __forceinline__ float bf2f(u16 u) {
  unsigned int x = ((unsigned int)u) << 16;
  return __builtin_bit_cast(float, x);
}
__device__ __forceinline__ u16 f2bf(float f) {  // RNE
  unsigned int x = __builtin_bit_cast(unsigned int, f);
  x += 0x7FFFu + ((x >> 16) & 1u);
  return (u16)(x >> 16);
}

// p = exp(sv/8) = exp2(sv * 0.125*log2(e)), arg clamped to +-43.28 (= exp +-30)
__device__ __forceinline__ float expfast(float sv) {
  const float x =
      __builtin_amdgcn_fmed3f(sv * 0.18033688011112042f, -43.2809f, 43.2809f);
#if __has_builtin(__builtin_amdgcn_exp2f)
  return __builtin_amdgcn_exp2f(x);
#else
  return __expf(x * 0.6931471805599453f);
#endif
}

// pack two f32 -> u32 of 2 bf16 (lo = first arg), RNE
__device__ __forceinline__ u32 cvtpk(float lo, float hi) {
  u32 r;
  asm("v_cvt_pk_bf16_f32 %0, %1, %2" : "=v"(r) : "v"(lo), "v"(hi));
  return r;
}

// a.upper <-> b.lower (lanes 32-63 of a get b's lanes 0-31, and vice versa)
__device__ __forceinline__ void plswap(u32& a, u32& b) {
  asm volatile("v_permlane32_swap_b32 %0, %1" : "+v"(a), "+v"(b));
}

#if __has_builtin(__builtin_amdgcn_global_load_lds)
#define HAVE_GLDS 1
// dest is wave-uniform base; HW writes lane i at base + i*16B
__device__ __forceinline__ void glds16(const u16* g, u16* l) {
  __builtin_amdgcn_global_load_lds(
      (const __attribute__((address_space(1))) void*)g,
      (__attribute__((address_space(3))) void*)l, 16, 0, 0);
}
#else
#define HAVE_GLDS 0
#endif

// ---- bulk fp32 -> bf16 converter over 8 segments ----
struct Cvt8 {
  const float* s[8];
  u16* d[8];
};
__global__ __launch_bounds__(256) void cvt_k(Cvt8 a) {
  const size_t t = ((size_t)blockIdx.x * 256 + threadIdx.x) * 4;
  const size_t cum[9] = {0,        4194304,  8388608,  12582912, 13369344,
                         13631488, 13633024, 13633536, 13634048};
  if (t >= cum[8]) return;
  int sg = 0;
#pragma unroll
  for (int i = 1; i < 8; i++) sg += (t >= cum[i]);
  const size_t off = t - cum[sg];
  const v4f x = *(const v4f*)(a.s[sg] + off);
  ushort4 o;
  o.x = f2bf(x[0]);
  o.y = f2bf(x[1]);
  o.z = f2bf(x[2]);
  o.w = f2bf(x[3]);
  *(ushort4*)(a.d[sg] + off) = o;
}

// ---------------- NT GEMM core: C(128x128) = A(Mx512) * W(512 rows)^T ------
// R11: BK=64. LDS = 8 k-octet planes (stride 1032 shorts). Wave w stages
// planes w (k-octet w) and w+4 (k-octet w+4) via glds width=16. Two MFMA
// k-steps per round read planes [0..3] then [4..7]. 16 barriers/block.
__device__ __forceinline__ void gemm_core(const u16* A, const u16* W, int m0,
                                          int n0, u16* As, u16* Bs,
                                          v4f acc[4][4]) {
  const int lane = threadIdx.x & 63;
  const int w = threadIdx.x >> 6;
  const int wr = w >> 1, wc = w & 1;
  const int q = lane >> 4, c = lane & 15;
#pragma unroll
  for (int i = 0; i < 4; i++)
#pragma unroll
    for (int j = 0; j < 4; j++) acc[i][j] = (v4f){0.f, 0.f, 0.f, 0.f};
  for (int kk = 0; kk < 8; ++kk) {  // 64-k steps
    const u16* ga = A + (size_t)(m0 + lane) * E_D + kk * 64 + w * 8;
    const u16* gb = W + (size_t)(n0 + lane) * E_D + kk * 64 + w * 8;
#if HAVE_GLDS
    __syncthreads();  // prior round's frag reads done before overwrite
    glds16(ga, As + w * 1032);
    glds16(ga + 64 * E_D, As + w * 1032 + 512);
    glds16(ga + 32, As + (w + 4) * 1032);
    glds16(ga + 32 + 64 * E_D, As + (w + 4) * 1032 + 512);
    glds16(gb, Bs + w * 1032);
    glds16(gb + 64 * E_D, Bs + w * 1032 + 512);
    glds16(gb + 32, Bs + (w + 4) * 1032);
    glds16(gb + 32 + 64 * E_D, Bs + (w + 4) * 1032 + 512);
    __syncthreads();  // drains vmcnt -> LDS ready
#else
    const v8s va0 = *(const v8s*)ga;
    const v8s va1 = *(const v8s*)(ga + 64 * E_D);
    const v8s va2 = *(const v8s*)(ga + 32);
    const v8s va3 = *(const v8s*)(ga + 32 + 64 * E_D);
    const v8s vb0 = *(const v8s*)gb;
    const v8s vb1 = *(const v8s*)(gb + 64 * E_D);
    const v8s vb2 = *(const v8s*)(gb + 32);
    const v8s vb3 = *(const v8s*)(gb + 32 + 64 * E_D);
    __syncthreads();
    *(v8s*)(As + w * 1032 + lane * 8) = va0;
    *(v8s*)(As + w * 1032 + 512 + lane * 8) = va1;
    *(v8s*)(As + (w + 4) * 1032 + lane * 8) = va2;
    *(v8s*)(As + (w + 4) * 1032 + 512 + lane * 8) = va3;
    *(v8s*)(Bs + w * 1032 + lane * 8) = vb0;
    *(v8s*)(Bs + w * 1032 + 512 + lane * 8) = vb1;
    *(v8s*)(Bs + (w + 4) * 1032 + lane * 8) = vb2;
    *(v8s*)(Bs + (w + 4) * 1032 + 512 + lane * 8) = vb3;
    __syncthreads();
#endif
#pragma unroll
    for (int t = 0; t < 2; t++) {
      v8s a[4], b[4];
#pragma unroll
      for (int i = 0; i < 4; i++)
        a[i] =
            *(const v8s*)(As + (t * 4 + q) * 1032 + (wr * 64 + i * 16 + c) * 8);
#pragma unroll
      for (int j = 0; j < 4; j++)
        b[j] =
            *(const v8s*)(Bs + (t * 4 + q) * 1032 + (wc * 64 + j * 16 + c) * 8);
#pragma unroll
      for (int i = 0; i < 4; i++)
#pragma unroll
        for (int j = 0; j < 4; j++) acc[i][j] = MFMA16(a[i], b[j], acc[i][j]);
    }
  }
}

// qkv projections (all-bf16). z=0: Qw[n][h][l][d] = q + bias + rel_u
//   z=1: Kw[n][h][s][d]   z=2: Vt[n][h][d][s] (transposed for PV)
__global__ __launch_bounds__(256) void gemm_qkv(
    const u16* __restrict__ qb, const u16* __restrict__ kb,
    const u16* __restrict__ vb, const u16* __restrict__ Wallb,
    const u16* __restrict__ biasb, const u16* __restrict__ rel_ub,
    u16* __restrict__ Qw, u16* __restrict__ Kw, u16* __restrict__ Vt) {
  __shared__ __align__(16) u16 As[8 * 1032];
  __shared__ __align__(16) u16 Bs[8 * 1032];
  const int z = blockIdx.z;
  const u16* A = (z == 0) ? qb : ((z == 1) ? kb : vb);
  const int m0 = blockIdx.x * 128, n0 = blockIdx.y * 128;
  v4f acc[4][4];
  gemm_core(A, Wallb + (size_t)z * E_D * E_D, m0, n0, As, Bs, acc);
  const int lane = threadIdx.x & 63, w = threadIdx.x >> 6;
  const int wr = w >> 1, wc = w & 1;
  const int q = lane >> 4, c = lane & 15;
#pragma unroll
  for (int j = 0; j < 4; j++) {
    const int jg = n0 + wc * 64 + j * 16 + c;  // output feature = h*64+d
    const int h = jg >> 6, d = jg & 63;
    float add =
        bf2f(biasb[z * E_D + jg]) + ((z == 0) ? bf2f(rel_ub[jg]) : 0.f);
#pragma unroll
    for (int i = 0; i < 4; i++) {
#pragma unroll
      for (int r = 0; r < 4; r++) {
        const int mg = m0 + wr * 64 + i * 16 + q * 4 + r;  // row = l*4+n
        const int row = mg >> 2, nn = mg & 3;
        const u16 o = f2bf(acc[i][j][r] + add);
        if (z == 0)
          Qw[((size_t)(nn * H_N + h) * L_Q + row) * D_H + d] = o;
        else if (z == 1)
          Kw[((size_t)(nn * H_N + h) * S_K + row) * D_H + d] = o;
        else
          Vt[((size_t)(nn * H_N + h) * D_H + d) * S_K + row] = o;
      }
    }
  }
}

// out = Actx(8192x512)bf16 @ Woutb^T + bout -> fp32 d_out[0 : L*N*E)
__global__ __launch_bounds__(256) void gemm_out(const u16* __restrict__ Actx,
                                                const u16* __restrict__ Woutb,
                                                const u16* __restrict__ boutb,
                                                float* __restrict__ out) {
  __shared__ __align__(16) u16 As[8 * 1032];
  __shared__ __align__(16) u16 Bs[8 * 1032];
  const int m0 = blockIdx.x * 128, n0 = blockIdx.y * 128;
  v4f acc[4][4];
  gemm_core(Actx, Woutb, m0, n0, As, Bs, acc);
  const int lane = threadIdx.x & 63, w = threadIdx.x >> 6;
  const int wr = w >> 1, wc = w & 1;
  const int q = lane >> 4, c = lane & 15;
#pragma unroll
  for (int j = 0; j < 4; j++) {
    const int jg = n0 + wc * 64 + j * 16 + c;
    const float bb = bf2f(boutb[jg]);
#pragma unroll
    for (int i = 0; i < 4; i++) {
#pragma unroll
      for (int r = 0; r < 4; r++) {
        const int mg = m0 + wr * 64 + i * 16 + q * 4 + r;
        out[(size_t)mg * E_D + jg] = acc[i][j][r] + bb;
      }
    }
  }
}

// Flash pass, 32x32x16 form (R9). Block = 128 l (32 per wave), chunk = 64 s.
// QK^T as mfma(K,Q) => D = S^T[s][l], lane holds 32 s-values for its own l.
// P in-register: expfast -> cvt_pk bf16 pairs -> permlane32_swap builds the
// PV B-operand. PV: O^T[d][l] = V^T[d][s] @ P^T[s][l].
// Double-buffered Ks/Vs (1 barrier/chunk) + next-chunk K/V reg prefetch.
__global__ __launch_bounds__(256) void flash_pv(
    const u16* __restrict__ Qw, const u16* __restrict__ Kw,
    const u16* __restrict__ Vt, u16* __restrict__ Actx,
    float* __restrict__ Rbuf) {
  __shared__ __align__(16) u16 Ks[2][8 * 520];  // plane = d-octet, idx = s
  __shared__ __align__(16) u16 Vs[2][8 * 520];  // plane = s-octet, idx = d
  const int lane = threadIdx.x & 63, w = threadIdx.x >> 6;
  const int ln = lane & 31, hi = lane >> 5;
  // bijective XCD swizzle: 512 blocks = 8 xcd * 64; xcd gets 4 contig nh's
  const int orig = (blockIdx.x & 7) * 64 + (blockIdx.x >> 3);
  const int l0 = (orig & 15) * 128;
  const int h = (orig >> 4) & 7;
  const int n = orig >> 7;
  const int nh = n * H_N + h;
  // Q B-fragments direct from global (row l, k = d = kt*16 + hi*8 + j)
  v8s aq[4];
  {
    const u16* gq = Qw + ((size_t)nh * L_Q + l0 + w * 32 + ln) * D_H + hi * 8;
#pragma unroll
    for (int kt = 0; kt < 4; kt++) aq[kt] = *(const v8s*)(gq + kt * 16);
  }
  v16f ctx[2];
  ctx[0] = (v16f)0.f;
  ctx[1] = (v16f)0.f;
  float s_run = 0.f;
  // prefetch chunk 0 into regs
  const u16* gk = Kw + ((size_t)nh * S_K + lane) * D_H + w * 8;
  const u16* gv = Vt + ((size_t)nh * D_H + lane) * S_K + w * 8;
  v8s vk0 = *(const v8s*)gk;
  v8s vk1 = *(const v8s*)(gk + 32);
  v8s vv0 = *(const v8s*)gv;
  v8s vv1 = *(const v8s*)(gv + 32);
  int p = 0;
  for (int s0 = 0; s0 < S_K; s0 += 64, p ^= 1) {
    // stage current chunk (regs -> LDS buf p); prior reads of buf p finished
    // before the previous barrier
    *(v8s*)(Ks[p] + w * 520 + lane * 8) = vk0;
    *(v8s*)(Ks[p] + (w + 4) * 520 + lane * 8) = vk1;
    *(v8s*)(Vs[p] + w * 520 + lane * 8) = vv0;
    *(v8s*)(Vs[p] + (w + 4) * 520 + lane * 8) = vv1;
    __syncthreads();
    // issue next chunk's loads; latency hides under this chunk's compute
    if (s0 + 64 < S_K) {
      gk += 64 * D_H;  // next 64 s-rows
      gv += 64;        // next 64 s-cols
      vk0 = *(const v8s*)gk;
      vk1 = *(const v8s*)(gk + 32);
      vv0 = *(const v8s*)gv;
      vv1 = *(const v8s*)(gv + 32);
    }
    // QK: two 32-s tiles; A = K[s][d] (row=ln), B = Q (col=ln)
    v8s pb[4];  // PV B-frags: P^T slot ks covers s = ks*16 + hi*8 + j
#pragma unroll
    for (int st = 0; st < 2; st++) {
      v16f zz = (v16f)0.f;
#pragma unroll
      for (int kt = 0; kt < 4; kt++) {
        const v8s bk =
            *(const v8s*)(Ks[p] + (kt * 2 + hi) * 520 + (st * 32 + ln) * 8);
        zz = MFMA32(bk, aq[kt], zz);
      }
      // lane's s-coverage: st*32 + (r&3) + 8*(r>>2) + 4*hi, r = 0..15
      float pv[16];
#pragma unroll
      for (int r = 0; r < 16; r++) {
        pv[r] = expfast(zz[r]);
        s_run += pv[r];
      }
#pragma unroll
      for (int half = 0; half < 2; half++) {
        const int rb = half * 8;
        u32 a0 = cvtpk(pv[rb + 0], pv[rb + 1]);
        u32 b0 = cvtpk(pv[rb + 4], pv[rb + 5]);
        u32 a1 = cvtpk(pv[rb + 2], pv[rb + 3]);
        u32 b1 = cvtpk(pv[rb + 6], pv[rb + 7]);
        plswap(a0, b0);  // a0 -> word0 (s+0,1|8,9), b0 -> word2 (s+4,5|12,13)
        plswap(a1, b1);  // a1 -> word1,  b1 -> word3
        v4u t;
        t.x = a0;
        t.y = a1;
        t.z = b0;
        t.w = b1;
        pb[st * 2 + half] = __builtin_bit_cast(v8s, t);
      }
    }
    // PV: O^T[d][l]; A = V^T[d][s] (row=ln), B = P^T (col=ln)
#pragma unroll
    for (int dt = 0; dt < 2; dt++) {
#pragma unroll
      for (int ks = 0; ks < 4; ks++) {
        const v8s av =
            *(const v8s*)(Vs[p] + (ks * 2 + hi) * 520 + (dt * 32 + ln) * 8);
        ctx[dt] = MFMA32(av, pb[ks], ctx[dt]);
      }
    }
  }
  // full row sum: lane covers half the s-values, partner lane^32 the rest
  const float s = s_run + __shfl_xor(s_run, 32);
  const float rr = 1.0f / s;
  const int l = l0 + w * 32 + ln;
  u16* pout = Actx + ((size_t)l * N_B + n) * E_D + h * D_H;
#pragma unroll
  for (int dt = 0; dt < 2; dt++) {
#pragma unroll
    for (int g = 0; g < 4; g++) {
      const int d = dt * 32 + g * 8 + hi * 4;  // 4 consecutive d per group
      uint2 o;
      o.x = cvtpk(ctx[dt][g * 4 + 0] * rr, ctx[dt][g * 4 + 1] * rr);
      o.y = cvtpk(ctx[dt][g * 4 + 2] * rr, ctx[dt][g * 4 + 3] * rr);
      *(uint2*)(pout + d) = o;
    }
  }
  if (hi == 0) Rbuf[(size_t)nh * L_Q + l] = rr;  // 32 consecutive floats
}

// attw pass (runs LAST; overwrites the d_out scratch region with the real
// attention-weight output): per (n, l-tile 64, s-chunk 256): loop h (runtime,
// addresses only) with FULLY UNROLLED ss so every aw[ss][jt] index is
// compile-time (rule #20). Double-buffered Qs/Ks (1 barrier/iter) + next
// chunk's K (and Q at h-boundary) prefetched into regs under compute.
__global__ __launch_bounds__(256) void attw_k(const u16* __restrict__ Qw,
                                              const u16* __restrict__ Kw,
                                              const float* __restrict__ Rbuf,
                                              float* __restrict__ AW) {
  __shared__ __align__(16) u16 Qs[2][8 * 520];
  __shared__ __align__(16) u16 Ks[2][8 * 520];
  const int lane = threadIdx.x & 63, w = threadIdx.x >> 6;
  const int q = lane >> 4, c = lane & 15;
  const int s_base = blockIdx.x * 256;
  const int l0 = blockIdx.y * 64;
  const int n = blockIdx.z;
  v4f aw[4][4];
#pragma unroll
  for (int ss = 0; ss < 4; ss++)
#pragma unroll
    for (int jt = 0; jt < 4; jt++) aw[ss][jt] = (v4f){0.f, 0.f, 0.f, 0.f};
  // prologue prefetch: h=0 Q tile + (h=0, ss=0) K chunk
  v8s vq0, vq1, vk0, vk1;
  {
    const u16* g = Qw + ((size_t)(n * H_N) * L_Q + l0 + lane) * D_H + w * 8;
    vq0 = *(const v8s*)g;
    vq1 = *(const v8s*)(g + 32);
    const u16* gk =
        Kw + ((size_t)(n * H_N) * S_K + s_base + lane) * D_H + w * 8;
    vk0 = *(const v8s*)gk;
    vk1 = *(const v8s*)(gk + 32);
  }
  v8s aq0, aq1;
  float rr[4];
  for (int h = 0; h < H_N; ++h) {
    const int hp = h & 1;  // LDS buffer parity for Q (address only)
#pragma unroll
    for (int ss = 0; ss < 4; ++ss) {  // static: aw indices compile-time
      const int p = ss & 1;           // (h*4+ss)&1 == ss&1, compile-time
      // stage current regs
      if (ss == 0) {
        *(v8s*)(Qs[hp] + w * 520 + lane * 8) = vq0;
        *(v8s*)(Qs[hp] + (w + 4) * 520 + lane * 8) = vq1;
      }
      *(v8s*)(Ks[p] + w * 520 + lane * 8) = vk0;
      *(v8s*)(Ks[p] + (w + 4) * 520 + lane * 8) = vk1;
      __syncthreads();
      // prefetch next (h,ss) chunk's K (and Q at h boundary)
      if (h * 4 + ss + 1 < 32) {
        const int h2 = (ss == 3) ? h + 1 : h;
        const int ss2 = (ss == 3) ? 0 : ss + 1;
        const u16* gk =
            Kw +
            ((size_t)(n * H_N + h2) * S_K + s_base + ss2 * 64 + lane) * D_H +
            w * 8;
        vk0 = *(const v8s*)gk;
        vk1 = *(const v8s*)(gk + 32);
        if (ss2 == 0) {
          const u16* g =
              Qw + ((size_t)(n * H_N + h2) * L_Q + l0 + lane) * D_H + w * 8;
          vq0 = *(const v8s*)g;
          vq1 = *(const v8s*)(g + 32);
        }
      }
      if (ss == 0) {
        aq0 = *(const v8s*)(Qs[hp] + q * 520 + (w * 16 + c) * 8);
        aq1 = *(const v8s*)(Qs[hp] + (q + 4) * 520 + (w * 16 + c) * 8);
#pragma unroll
        for (int r = 0; r < 4; r++)
          rr[r] = Rbuf[(size_t)(n * H_N + h) * L_Q + l0 + w * 16 + q * 4 + r];
      }
#pragma unroll
      for (int jt = 0; jt < 4; jt++) {
        const v8s bk0 = *(const v8s*)(Ks[p] + q * 520 + (jt * 16 + c) * 8);
        const v8s bk1 =
            *(const v8s*)(Ks[p] + (q + 4) * 520 + (jt * 16 + c) * 8);
        v4f zz = (v4f){0.f, 0.f, 0.f, 0.f};
        zz = MFMA16(aq0, bk0, zz);
        zz = MFMA16(aq1, bk1, zz);
#pragma unroll
        for (int r = 0; r < 4; r++) aw[ss][jt][r] += expfast(zz[r]) * rr[r];
      }
    }
  }
#pragma unroll
  for (int ss = 0; ss < 4; ss++)
#pragma unroll
    for (int jt = 0; jt < 4; jt++)
#pragma unroll
      for (int r = 0; r < 4; r++) {
        const int l = l0 + w * 16 + q * 4 + r;
        const int s = s_base + ss * 64 + jt * 16 + c;
        AW[((size_t)n * L_Q + l) * S_K + s] = aw[ss][jt][r] * 0.125f;
      }
}

extern "C" void kernel_launch(void* const* d_in, const int* in_sizes, int n_in,
                              void* d_out, int out_size, void* d_ws,
                              size_t ws_size, hipStream_t stream) {
  // ws layout (<= 29.7 MB, proven safe at 33.8 in R4)
  char* ws = (char*)d_ws;
  u16* Wallb = (u16*)(ws);                 // 1.57 MB
  u16* Woutb = (u16*)(ws + 1572864);       // 0.52 MB
  u16* biasb = (u16*)(ws + 2097152);       // 3 KB
  u16* boutb = (u16*)(ws + 2100224);       // 1 KB
  u16* rel_ub = (u16*)(ws + 2101248);      // 1 KB
  u16* Qw = (u16*)(ws + 4194304);          // 8 MB (N,H,L,D)
  u16* Kw = (u16*)(ws + 12582912);         // 8 MB (N,H,S,D)
  u16* Vt = (u16*)(ws + 20971520);         // 8 MB (N,H,D,S)
  float* Rbuf = (float*)(ws + 29360128);   // 256 KB (N*H, L)

  // scratch inside d_out's attw region (67 MB; overwritten by attw_k LAST)
  float* out = (float*)d_out;
  char* sc = (char*)d_out + 16777216;
  u16* qb = (u16*)(sc);              // 8 MB converted query
  u16* kb = (u16*)(sc + 8388608);    // 8 MB converted key
  u16* vb = (u16*)(sc + 16777216);   // 8 MB converted value
  u16* Actx = (u16*)(sc + 25165824); // 8 MB context (L*4+n, E)
  float* AW = out + (size_t)L_Q * N_B * E_D;

  Cvt8 a;
  a.s[0] = (const float*)d_in[0];  a.d[0] = qb;      // query
  a.s[1] = (const float*)d_in[1];  a.d[1] = kb;      // key
  a.s[2] = (const float*)d_in[2];  a.d[2] = vb;      // value
  a.s[3] = (const float*)d_in[4];  a.d[3] = Wallb;   // in_proj_weight
  a.s[4] = (const float*)d_in[6];  a.d[4] = Woutb;   // out_w
  a.s[5] = (const float*)d_in[5];  a.d[5] = biasb;   // in_proj_bias
  a.s[6] = (const float*)d_in[7];  a.d[6] = boutb;   // out_b
  a.s[7] = (const float*)d_in[9];  a.d[7] = rel_ub;  // rel_u
  // d_in[3] sin_pos_enc, d_in[8] rel_proj_w, d_in[10] rel_v: algebraically out

  hipLaunchKernelGGL(cvt_k, dim3(13315), dim3(256), 0, stream, a);
  hipLaunchKernelGGL(gemm_qkv, dim3(64, 4, 3), dim3(256), 0, stream, qb, kb,
                     vb, Wallb, biasb, rel_ub, Qw, Kw, Vt);
  hipLaunchKernelGGL(flash_pv, dim3(512), dim3(256), 0, stream, Qw, Kw, Vt,
                     Actx, Rbuf);
  hipLaunchKernelGGL(gemm_out, dim3(64, 4, 1), dim3(256), 0, stream, Actx,
                     Woutb, boutb, out);
  hipLaunchKernelGGL(attw_k, dim3(8, 32, 4), dim3(256), 0, stream, Qw, Kw,
                     Rbuf, AW);
}

// Round 7
// 296.089 us; speedup vs baseline: 1.6057x; 1.0399x over previous
//
#include <hip/hip_runtime.h>
#include <hip/hip_bf16.h>
#include <stdint.h>

// XL multihead attention, L=S=2048, N=4, E=512, H=8, D=64.  I/O = fp32.
// _rel_shift collapses to a per-row constant (softmax-invariant) => term_bd,
// rel_v, sin_pos_enc, rel_proj_w drop out. Remaining: MHA with rel_u q-bias
// + head-mean att weights.
// R12: (a) revert gemm_core to BK=32 (R11's BK=64 cost ~6us: 33KB LDS cut
// GEMM occupancy more than halved barriers saved -- m132 lesson). (b) fold
// softmax scale 0.125*log2(e) into Q at gemm_qkv epilogue; expfast loses its
// v_mul in BOTH flash_pv (32/chunk) and attw_k (64/h-iter). Same numerics.

#define L_Q 2048
#define S_K 2048
#define N_B 4
#define E_D 512
#define H_N 8
#define D_H 64

typedef unsigned short u16;
typedef unsigned int u32;
typedef short v8s __attribute__((ext_vector_type(8)));
typedef float v4f __attribute__((ext_vector_type(4)));
typedef float v16f __attribute__((ext_vector_type(16)));
typedef u32 v4u __attribute__((ext_vector_type(4)));

#define MFMA16(a, b, c) __builtin_amdgcn_mfma_f32_16x16x32_bf16(a, b, c, 0, 0, 0)
#define MFMA32(a, b, c) __builtin_amdgcn_mfma_f32_32x32x16_bf16(a, b, c, 0, 0, 0)

// softmax scale folded into Q: exp(s/8) = exp2(sQK) with Q pre-scaled by this
#define QSCALE 0.18033688011112042f  // 0.125 * log2(e)

__device__ __forceinline__ float bf2f(u16 u) {
  unsigned int x = ((unsigned int)u) << 16;
  return __builtin_bit_cast(float, x);
}
__device__ __forceinline__ u16 f2bf(float f) {  // RNE
  unsigned int x = __builtin_bit_cast(unsigned int, f);
  x += 0x7FFFu + ((x >> 16) & 1u);
  return (u16)(x >> 16);
}

// p = exp2(zz), zz already includes the folded softmax scale; clamp +-43.28
// (= exp +-30) keeps everything finite.
__device__ __forceinline__ float expfast(float zz) {
  const float x = __builtin_amdgcn_fmed3f(zz, -43.2809f, 43.2809f);
#if __has_builtin(__builtin_amdgcn_exp2f)
  return __builtin_amdgcn_exp2f(x);
#else
  return __expf(x * 0.6931471805599453f);
#endif
}

// pack two f32 -> u32 of 2 bf16 (lo = first arg), RNE
__device__ __forceinline__ u32 cvtpk(float lo, float hi) {
  u32 r;
  asm("v_cvt_pk_bf16_f32 %0, %1, %2" : "=v"(r) : "v"(lo), "v"(hi));
  return r;
}

// a.upper <-> b.lower (lanes 32-63 of a get b's lanes 0-31, and vice versa)
__device__ __forceinline__ void plswap(u32& a, u32& b) {
  asm volatile("v_permlane32_swap_b32 %0, %1" : "+v"(a), "+v"(b));
}

#if __has_builtin(__builtin_amdgcn_global_load_lds)
#define HAVE_GLDS 1
// dest is wave-uniform base; HW writes lane i at base + i*16B
__device__ __forceinline__ void glds16(const u16* g, u16* l) {
  __builtin_amdgcn_global_load_lds(
      (const __attribute__((address_space(1))) void*)g,
      (__attribute__((address_space(3))) void*)l, 16, 0, 0);
}
#else
#define HAVE_GLDS 0
#endif

// ---- bulk fp32 -> bf16 converter over 8 segments ----
struct Cvt8 {
  const float* s[8];
  u16* d[8];
};
__global__ __launch_bounds__(256) void cvt_k(Cvt8 a) {
  const size_t t = ((size_t)blockIdx.x * 256 + threadIdx.x) * 4;
  const size_t cum[9] = {0,        4194304,  8388608,  12582912, 13369344,
                         13631488, 13633024, 13633536, 13634048};
  if (t >= cum[8]) return;
  int sg = 0;
#pragma unroll
  for (int i = 1; i < 8; i++) sg += (t >= cum[i]);
  const size_t off = t - cum[sg];
  const v4f x = *(const v4f*)(a.s[sg] + off);
  ushort4 o;
  o.x = f2bf(x[0]);
  o.y = f2bf(x[1]);
  o.z = f2bf(x[2]);
  o.w = f2bf(x[3]);
  *(ushort4*)(a.d[sg] + off) = o;
}

// ---------------- NT GEMM core: C(128x128) = A(Mx512) * W(512 rows)^T ------
// BK=32 (proven best). LDS: 4 k-octet planes, stride 1032 shorts. Wave w
// stages plane w via glds width=16 (lane i -> base + i*16B).
__device__ __forceinline__ void gemm_core(const u16* A, const u16* W, int m0,
                                          int n0, u16* As, u16* Bs,
                                          v4f acc[4][4]) {
  const int lane = threadIdx.x & 63;
  const int w = threadIdx.x >> 6;
  const int wr = w >> 1, wc = w & 1;
  const int q = lane >> 4, c = lane & 15;
#pragma unroll
  for (int i = 0; i < 4; i++)
#pragma unroll
    for (int j = 0; j < 4; j++) acc[i][j] = (v4f){0.f, 0.f, 0.f, 0.f};
  for (int kk = 0; kk < 16; ++kk) {
    const u16* ga = A + (size_t)(m0 + lane) * E_D + kk * 32 + w * 8;
    const u16* gb = W + (size_t)(n0 + lane) * E_D + kk * 32 + w * 8;
#if HAVE_GLDS
    __syncthreads();  // prior iteration's reads done before overwrite
    glds16(ga, As + w * 1032);
    glds16(ga + 64 * E_D, As + w * 1032 + 512);
    glds16(gb, Bs + w * 1032);
    glds16(gb + 64 * E_D, Bs + w * 1032 + 512);
    __syncthreads();  // drains vmcnt -> LDS ready
#else
    const v8s va0 = *(const v8s*)ga;
    const v8s va1 = *(const v8s*)(ga + 64 * E_D);
    const v8s vb0 = *(const v8s*)gb;
    const v8s vb1 = *(const v8s*)(gb + 64 * E_D);
    __syncthreads();
    *(v8s*)(As + w * 1032 + lane * 8) = va0;
    *(v8s*)(As + w * 1032 + 512 + lane * 8) = va1;
    *(v8s*)(Bs + w * 1032 + lane * 8) = vb0;
    *(v8s*)(Bs + w * 1032 + 512 + lane * 8) = vb1;
    __syncthreads();
#endif
    v8s a[4], b[4];
#pragma unroll
    for (int i = 0; i < 4; i++)
      a[i] = *(const v8s*)(As + q * 1032 + (wr * 64 + i * 16 + c) * 8);
#pragma unroll
    for (int j = 0; j < 4; j++)
      b[j] = *(const v8s*)(Bs + q * 1032 + (wc * 64 + j * 16 + c) * 8);
#pragma unroll
    for (int i = 0; i < 4; i++)
#pragma unroll
      for (int j = 0; j < 4; j++) acc[i][j] = MFMA16(a[i], b[j], acc[i][j]);
  }
}

// qkv projections (all-bf16). z=0: Qw[n][h][l][d] = (q + bias + rel_u)*QSCALE
//   z=1: Kw[n][h][s][d]   z=2: Vt[n][h][d][s] (transposed for PV)
__global__ __launch_bounds__(256) void gemm_qkv(
    const u16* __restrict__ qb, const u16* __restrict__ kb,
    const u16* __restrict__ vb, const u16* __restrict__ Wallb,
    const u16* __restrict__ biasb, const u16* __restrict__ rel_ub,
    u16* __restrict__ Qw, u16* __restrict__ Kw, u16* __restrict__ Vt) {
  __shared__ __align__(16) u16 As[4 * 1032];
  __shared__ __align__(16) u16 Bs[4 * 1032];
  const int z = blockIdx.z;
  const u16* A = (z == 0) ? qb : ((z == 1) ? kb : vb);
  const int m0 = blockIdx.x * 128, n0 = blockIdx.y * 128;
  v4f acc[4][4];
  gemm_core(A, Wallb + (size_t)z * E_D * E_D, m0, n0, As, Bs, acc);
  const int lane = threadIdx.x & 63, w = threadIdx.x >> 6;
  const int wr = w >> 1, wc = w & 1;
  const int q = lane >> 4, c = lane & 15;
  const float scale = (z == 0) ? QSCALE : 1.0f;
#pragma unroll
  for (int j = 0; j < 4; j++) {
    const int jg = n0 + wc * 64 + j * 16 + c;  // output feature = h*64+d
    const int h = jg >> 6, d = jg & 63;
    float add =
        bf2f(biasb[z * E_D + jg]) + ((z == 0) ? bf2f(rel_ub[jg]) : 0.f);
#pragma unroll
    for (int i = 0; i < 4; i++) {
#pragma unroll
      for (int r = 0; r < 4; r++) {
        const int mg = m0 + wr * 64 + i * 16 + q * 4 + r;  // row = l*4+n
        const int row = mg >> 2, nn = mg & 3;
        const u16 o = f2bf((acc[i][j][r] + add) * scale);
        if (z == 0)
          Qw[((size_t)(nn * H_N + h) * L_Q + row) * D_H + d] = o;
        else if (z == 1)
          Kw[((size_t)(nn * H_N + h) * S_K + row) * D_H + d] = o;
        else
          Vt[((size_t)(nn * H_N + h) * D_H + d) * S_K + row] = o;
      }
    }
  }
}

// out = Actx(8192x512)bf16 @ Woutb^T + bout -> fp32 d_out[0 : L*N*E)
__global__ __launch_bounds__(256) void gemm_out(const u16* __restrict__ Actx,
                                                const u16* __restrict__ Woutb,
                                                const u16* __restrict__ boutb,
                                                float* __restrict__ out) {
  __shared__ __align__(16) u16 As[4 * 1032];
  __shared__ __align__(16) u16 Bs[4 * 1032];
  const int m0 = blockIdx.x * 128, n0 = blockIdx.y * 128;
  v4f acc[4][4];
  gemm_core(Actx, Woutb, m0, n0, As, Bs, acc);
  const int lane = threadIdx.x & 63, w = threadIdx.x >> 6;
  const int wr = w >> 1, wc = w & 1;
  const int q = lane >> 4, c = lane & 15;
#pragma unroll
  for (int j = 0; j < 4; j++) {
    const int jg = n0 + wc * 64 + j * 16 + c;
    const float bb = bf2f(boutb[jg]);
#pragma unroll
    for (int i = 0; i < 4; i++) {
#pragma unroll
      for (int r = 0; r < 4; r++) {
        const int mg = m0 + wr * 64 + i * 16 + q * 4 + r;
        out[(size_t)mg * E_D + jg] = acc[i][j][r] + bb;
      }
    }
  }
}

// Flash pass, 32x32x16 form. Block = 128 l (32 per wave), chunk = 64 s.
// QK^T as mfma(K,Q) => D = S^T[s][l], lane holds 32 s-values for its own l.
// P in-register: expfast -> cvt_pk bf16 pairs -> permlane32_swap builds the
// PV B-operand. PV: O^T[d][l] = V^T[d][s] @ P^T[s][l].
// Double-buffered Ks/Vs (1 barrier/chunk) + next-chunk K/V reg prefetch.
__global__ __launch_bounds__(256) void flash_pv(
    const u16* __restrict__ Qw, const u16* __restrict__ Kw,
    const u16* __restrict__ Vt, u16* __restrict__ Actx,
    float* __restrict__ Rbuf) {
  __shared__ __align__(16) u16 Ks[2][8 * 520];  // plane = d-octet, idx = s
  __shared__ __align__(16) u16 Vs[2][8 * 520];  // plane = s-octet, idx = d
  const int lane = threadIdx.x & 63, w = threadIdx.x >> 6;
  const int ln = lane & 31, hi = lane >> 5;
  // bijective XCD swizzle: 512 blocks = 8 xcd * 64; xcd gets 4 contig nh's
  const int orig = (blockIdx.x & 7) * 64 + (blockIdx.x >> 3);
  const int l0 = (orig & 15) * 128;
  const int h = (orig >> 4) & 7;
  const int n = orig >> 7;
  const int nh = n * H_N + h;
  // Q B-fragments direct from global (row l, k = d = kt*16 + hi*8 + j)
  v8s aq[4];
  {
    const u16* gq = Qw + ((size_t)nh * L_Q + l0 + w * 32 + ln) * D_H + hi * 8;
#pragma unroll
    for (int kt = 0; kt < 4; kt++) aq[kt] = *(const v8s*)(gq + kt * 16);
  }
  v16f ctx[2];
  ctx[0] = (v16f)0.f;
  ctx[1] = (v16f)0.f;
  float s_run = 0.f;
  // prefetch chunk 0 into regs
  const u16* gk = Kw + ((size_t)nh * S_K + lane) * D_H + w * 8;
  const u16* gv = Vt + ((size_t)nh * D_H + lane) * S_K + w * 8;
  v8s vk0 = *(const v8s*)gk;
  v8s vk1 = *(const v8s*)(gk + 32);
  v8s vv0 = *(const v8s*)gv;
  v8s vv1 = *(const v8s*)(gv + 32);
  int p = 0;
  for (int s0 = 0; s0 < S_K; s0 += 64, p ^= 1) {
    // stage current chunk (regs -> LDS buf p); prior reads of buf p finished
    // before the previous barrier
    *(v8s*)(Ks[p] + w * 520 + lane * 8) = vk0;
    *(v8s*)(Ks[p] + (w + 4) * 520 + lane * 8) = vk1;
    *(v8s*)(Vs[p] + w * 520 + lane * 8) = vv0;
    *(v8s*)(Vs[p] + (w + 4) * 520 + lane * 8) = vv1;
    __syncthreads();
    // issue next chunk's loads; latency hides under this chunk's compute
    if (s0 + 64 < S_K) {
      gk += 64 * D_H;  // next 64 s-rows
      gv += 64;        // next 64 s-cols
      vk0 = *(const v8s*)gk;
      vk1 = *(const v8s*)(gk + 32);
      vv0 = *(const v8s*)gv;
      vv1 = *(const v8s*)(gv + 32);
    }
    // QK: two 32-s tiles; A = K[s][d] (row=ln), B = Q (col=ln)
    v8s pb[4];  // PV B-frags: P^T slot ks covers s = ks*16 + hi*8 + j
#pragma unroll
    for (int st = 0; st < 2; st++) {
      v16f zz = (v16f)0.f;
#pragma unroll
      for (int kt = 0; kt < 4; kt++) {
        const v8s bk =
            *(const v8s*)(Ks[p] + (kt * 2 + hi) * 520 + (st * 32 + ln) * 8);
        zz = MFMA32(bk, aq[kt], zz);
      }
      // lane's s-coverage: st*32 + (r&3) + 8*(r>>2) + 4*hi, r = 0..15
      float pv[16];
#pragma unroll
      for (int r = 0; r < 16; r++) {
        pv[r] = expfast(zz[r]);
        s_run += pv[r];
      }
#pragma unroll
      for (int half = 0; half < 2; half++) {
        const int rb = half * 8;
        u32 a0 = cvtpk(pv[rb + 0], pv[rb + 1]);
        u32 b0 = cvtpk(pv[rb + 4], pv[rb + 5]);
        u32 a1 = cvtpk(pv[rb + 2], pv[rb + 3]);
        u32 b1 = cvtpk(pv[rb + 6], pv[rb + 7]);
        plswap(a0, b0);  // a0 -> word0 (s+0,1|8,9), b0 -> word2 (s+4,5|12,13)
        plswap(a1, b1);  // a1 -> word1,  b1 -> word3
        v4u t;
        t.x = a0;
        t.y = a1;
        t.z = b0;
        t.w = b1;
        pb[st * 2 + half] = __builtin_bit_cast(v8s, t);
      }
    }
    // PV: O^T[d][l]; A = V^T[d][s] (row=ln), B = P^T (col=ln)
#pragma unroll
    for (int dt = 0; dt < 2; dt++) {
#pragma unroll
      for (int ks = 0; ks < 4; ks++) {
        const v8s av =
            *(const v8s*)(Vs[p] + (ks * 2 + hi) * 520 + (dt * 32 + ln) * 8);
        ctx[dt] = MFMA32(av, pb[ks], ctx[dt]);
      }
    }
  }
  // full row sum: lane covers half the s-values, partner lane^32 the rest
  const float s = s_run + __shfl_xor(s_run, 32);
  const float rr = 1.0f / s;
  const int l = l0 + w * 32 + ln;
  u16* pout = Actx + ((size_t)l * N_B + n) * E_D + h * D_H;
#pragma unroll
  for (int dt = 0; dt < 2; dt++) {
#pragma unroll
    for (int g = 0; g < 4; g++) {
      const int d = dt * 32 + g * 8 + hi * 4;  // 4 consecutive d per group
      uint2 o;
      o.x = cvtpk(ctx[dt][g * 4 + 0] * rr, ctx[dt][g * 4 + 1] * rr);
      o.y = cvtpk(ctx[dt][g * 4 + 2] * rr, ctx[dt][g * 4 + 3] * rr);
      *(uint2*)(pout + d) = o;
    }
  }
  if (hi == 0) Rbuf[(size_t)nh * L_Q + l] = rr;  // 32 consecutive floats
}

// attw pass (runs LAST; overwrites the d_out scratch region with the real
// attention-weight output): per (n, l-tile 64, s-chunk 256): loop h (runtime,
// addresses only) with FULLY UNROLLED ss so every aw[ss][jt] index is
// compile-time (rule #20). Double-buffered Qs/Ks (1 barrier/iter) + next
// chunk's K (and Q at h-boundary) prefetched into regs under compute.
__global__ __launch_bounds__(256) void attw_k(const u16* __restrict__ Qw,
                                              const u16* __restrict__ Kw,
                                              const float* __restrict__ Rbuf,
                                              float* __restrict__ AW) {
  __shared__ __align__(16) u16 Qs[2][8 * 520];
  __shared__ __align__(16) u16 Ks[2][8 * 520];
  const int lane = threadIdx.x & 63, w = threadIdx.x >> 6;
  const int q = lane >> 4, c = lane & 15;
  const int s_base = blockIdx.x * 256;
  const int l0 = blockIdx.y * 64;
  const int n = blockIdx.z;
  v4f aw[4][4];
#pragma unroll
  for (int ss = 0; ss < 4; ss++)
#pragma unroll
    for (int jt = 0; jt < 4; jt++) aw[ss][jt] = (v4f){0.f, 0.f, 0.f, 0.f};
  // prologue prefetch: h=0 Q tile + (h=0, ss=0) K chunk
  v8s vq0, vq1, vk0, vk1;
  {
    const u16* g = Qw + ((size_t)(n * H_N) * L_Q + l0 + lane) * D_H + w * 8;
    vq0 = *(const v8s*)g;
    vq1 = *(const v8s*)(g + 32);
    const u16* gk =
        Kw + ((size_t)(n * H_N) * S_K + s_base + lane) * D_H + w * 8;
    vk0 = *(const v8s*)gk;
    vk1 = *(const v8s*)(gk + 32);
  }
  v8s aq0, aq1;
  float rr[4];
  for (int h = 0; h < H_N; ++h) {
    const int hp = h & 1;  // LDS buffer parity for Q (address only)
#pragma unroll
    for (int ss = 0; ss < 4; ++ss) {  // static: aw indices compile-time
      const int p = ss & 1;           // (h*4+ss)&1 == ss&1, compile-time
      // stage current regs
      if (ss == 0) {
        *(v8s*)(Qs[hp] + w * 520 + lane * 8) = vq0;
        *(v8s*)(Qs[hp] + (w + 4) * 520 + lane * 8) = vq1;
      }
      *(v8s*)(Ks[p] + w * 520 + lane * 8) = vk0;
      *(v8s*)(Ks[p] + (w + 4) * 520 + lane * 8) = vk1;
      __syncthreads();
      // prefetch next (h,ss) chunk's K (and Q at h boundary)
      if (h * 4 + ss + 1 < 32) {
        const int h2 = (ss == 3) ? h + 1 : h;
        const int ss2 = (ss == 3) ? 0 : ss + 1;
        const u16* gk =
            Kw +
            ((size_t)(n * H_N + h2) * S_K + s_base + ss2 * 64 + lane) * D_H +
            w * 8;
        vk0 = *(const v8s*)gk;
        vk1 = *(const v8s*)(gk + 32);
        if (ss2 == 0) {
          const u16* g =
              Qw + ((size_t)(n * H_N + h2) * L_Q + l0 + lane) * D_H + w * 8;
          vq0 = *(const v8s*)g;
          vq1 = *(const v8s*)(g + 32);
        }
      }
      if (ss == 0) {
        aq0 = *(const v8s*)(Qs[hp] + q * 520 + (w * 16 + c) * 8);
        aq1 = *(const v8s*)(Qs[hp] + (q + 4) * 520 + (w * 16 + c) * 8);
#pragma unroll
        for (int r = 0; r < 4; r++)
          rr[r] = Rbuf[(size_t)(n * H_N + h) * L_Q + l0 + w * 16 + q * 4 + r];
      }
#pragma unroll
      for (int jt = 0; jt < 4; jt++) {
        const v8s bk0 = *(const v8s*)(Ks[p] + q * 520 + (jt * 16 + c) * 8);
        const v8s bk1 =
            *(const v8s*)(Ks[p] + (q + 4) * 520 + (jt * 16 + c) * 8);
        v4f zz = (v4f){0.f, 0.f, 0.f, 0.f};
        zz = MFMA16(aq0, bk0, zz);
        zz = MFMA16(aq1, bk1, zz);
#pragma unroll
        for (int r = 0; r < 4; r++) aw[ss][jt][r] += expfast(zz[r]) * rr[r];
      }
    }
  }
#pragma unroll
  for (int ss = 0; ss < 4; ss++)
#pragma unroll
    for (int jt = 0; jt < 4; jt++)
#pragma unroll
      for (int r = 0; r < 4; r++) {
        const int l = l0 + w * 16 + q * 4 + r;
        const int s = s_base + ss * 64 + jt * 16 + c;
        AW[((size_t)n * L_Q + l) * S_K + s] = aw[ss][jt][r] * 0.125f;
      }
}

extern "C" void kernel_launch(void* const* d_in, const int* in_sizes, int n_in,
                              void* d_out, int out_size, void* d_ws,
                              size_t ws_size, hipStream_t stream) {
  // ws layout (<= 29.7 MB, proven safe at 33.8 in R4)
  char* ws = (char*)d_ws;
  u16* Wallb = (u16*)(ws);                 // 1.57 MB
  u16* Woutb = (u16*)(ws + 1572864);       // 0.52 MB
  u16* biasb = (u16*)(ws + 2097152);       // 3 KB
  u16* boutb = (u16*)(ws + 2100224);       // 1 KB
  u16* rel_ub = (u16*)(ws + 2101248);      // 1 KB
  u16* Qw = (u16*)(ws + 4194304);          // 8 MB (N,H,L,D)
  u16* Kw = (u16*)(ws + 12582912);         // 8 MB (N,H,S,D)
  u16* Vt = (u16*)(ws + 20971520);         // 8 MB (N,H,D,S)
  float* Rbuf = (float*)(ws + 29360128);   // 256 KB (N*H, L)

  // scratch inside d_out's attw region (67 MB; overwritten by attw_k LAST)
  float* out = (float*)d_out;
  char* sc = (char*)d_out + 16777216;
  u16* qb = (u16*)(sc);              // 8 MB converted query
  u16* kb = (u16*)(sc + 8388608);    // 8 MB converted key
  u16* vb = (u16*)(sc + 16777216);   // 8 MB converted value
  u16* Actx = (u16*)(sc + 25165824); // 8 MB context (L*4+n, E)
  float* AW = out + (size_t)L_Q * N_B * E_D;

  Cvt8 a;
  a.s[0] = (const float*)d_in[0];  a.d[0] = qb;      // query
  a.s[1] = (const float*)d_in[1];  a.d[1] = kb;      // key
  a.s[2] = (const float*)d_in[2];  a.d[2] = vb;      // value
  a.s[3] = (const float*)d_in[4];  a.d[3] = Wallb;   // in_proj_weight
  a.s[4] = (const float*)d_in[6];  a.d[4] = Woutb;   // out_w
  a.s[5] = (const float*)d_in[5];  a.d[5] = biasb;   // in_proj_bias
  a.s[6] = (const float*)d_in[7];  a.d[6] = boutb;   // out_b
  a.s[7] = (const float*)d_in[9];  a.d[7] = rel_ub;  // rel_u
  // d_in[3] sin_pos_enc, d_in[8] rel_proj_w, d_in[10] rel_v: algebraically out

  hipLaunchKernelGGL(cvt_k, dim3(13315), dim3(256), 0, stream, a);
  hipLaunchKernelGGL(gemm_qkv, dim3(64, 4, 3), dim3(256), 0, stream, qb, kb,
                     vb, Wallb, biasb, rel_ub, Qw, Kw, Vt);
  hipLaunchKernelGGL(flash_pv, dim3(512), dim3(256), 0, stream, Qw, Kw, Vt,
                     Actx, Rbuf);
  hipLaunchKernelGGL(gemm_out, dim3(64, 4, 1), dim3(256), 0, stream, Actx,
                     Woutb, boutb, out);
  hipLaunchKernelGGL(attw_k, dim3(8, 32, 4), dim3(256), 0, stream, Qw, Kw,
                     Rbuf, AW);
}